// Round 5
// baseline (381.777 us; speedup 1.0000x reference)
//
#include <hip/hip_runtime.h>
#include <hip/hip_bf16.h>

// SelfBiLayer B=256,L=2048,E=64,DA=64,R=32 -- MFMA round 12.
// Rounds 10/11 falsified the DS-issue and barrier-vmcnt theories (both ~
// neutral). Remaining structural overhead in the ~51us non-fill budget:
// the separate reduce dispatch (launch/gap ~5-8us) + the accp HBM write->
// HBM re-read round-trip (8.4MB each way). Round 12 fuses finalization into
// selfbi_main via the last-block pattern: each (b,c) block atomicAdds its
// ssum partials to ssumg[b][r], release-fences, bumps cnt[b]; the block
// observing old==CH-1 acquire-fences and writes out[b] = sum_cc(accp)/den.
// accp re-reads hit L2/L3 (Infinity Cache is XCD-shared). ssumg+cnt zeroed
// by a 33KB hipMemsetAsync inside the graph. Reduce kernel deleted.
// In-loop barrier reverted to plain __syncthreads (round-11 lgkm-only
// variant measured neutral).
// Layout recap: x TOKEN-MAJOR in [e_tile(4)][tok_subtile(16)][4][16] bf16
// subtiles; GEMM3 B-frag via 4x ds_read_b64_tr_b16 (cooperative 16-lane
// granule read: lane addr = subtile_base + 8*ml -> lane gets column ml).
// Timed region note: ~156us of measured total is two 512MiB harness poison
// fills; controllable budget ~51us, HBM floor ~25us.
// Per block: (b, 512-token chunk), 8 sub-chunks of 64 tokens, 4 waves.

#define B_  256
#define L_  2048
#define E_  64
#define DA_ 64
#define R_  32
#define CH_ 4
#define NS_ 8
#define TL_ 64

typedef __attribute__((ext_vector_type(8))) short bf16x8;
typedef __attribute__((ext_vector_type(4))) float f32x4;
typedef __attribute__((ext_vector_type(2))) unsigned int u32x2;

// LDS (dword units).
#define HS_P 36
#define AS_P 36
#define HS_W (64 * HS_P)     // 2304
#define XT_W 2048            // per buffer: 4 e-tiles * 16 subtiles * 128B
#define AS_W (32 * AS_P)     // 1152 per buffer
// hs + 2*xt + 2*as + 128 ssl = 8832 words = 35328 B -> 4 blocks/CU

__device__ __forceinline__ unsigned pk(float a, float b) {
    __hip_bfloat162 h = __float22bfloat162_rn(float2{a, b});
    union { __hip_bfloat162 h2; unsigned u; } cv; cv.h2 = h;
    return cv.u;
}
__device__ __forceinline__ float bflo(unsigned u) { return __uint_as_float(u << 16); }
__device__ __forceinline__ float bfhi(unsigned u) { return __uint_as_float(u & 0xFFFF0000u); }
__device__ __forceinline__ float fast_tanh(float v) {
    float e = __builtin_amdgcn_exp2f(v * 2.885390082f);
    float r = __builtin_amdgcn_rcpf(e + 1.0f);
    return fmaf(-2.0f, r, 1.0f);
}
__device__ __forceinline__ float fast_exp(float v) {
    return __builtin_amdgcn_exp2f(v * 1.442695041f);
}

__launch_bounds__(256, 4)
__global__ void selfbi_main(const float* __restrict__ x,
                            const float* __restrict__ mask,
                            const float* __restrict__ W1,
                            const float* __restrict__ W2,
                            float* __restrict__ accp,
                            float* __restrict__ ssumg,
                            unsigned* __restrict__ cnt,
                            float* __restrict__ out) {
    __shared__ __align__(16) unsigned smem[HS_W + 2 * XT_W + 2 * AS_W + 128];
    unsigned* hsw  = smem;                       // H token-major, d-PERMUTED slots
    unsigned* xtw0 = smem + HS_W;                // x subtiled token-major, dbuf
    unsigned* asw0 = xtw0 + 2 * XT_W;            // asT[r][t], double-buffered
    float*    ssl  = (float*)(asw0 + 2 * AS_W);  // per-wave ssum partials

    const int b    = blockIdx.x;
    const int c    = blockIdx.y;
    const int tid  = threadIdx.x;
    const int w    = tid >> 6;
    const int lane = tid & 63;
    const int g    = lane >> 4;     // k-octet group
    const int ml   = lane & 15;     // m/n lane

    // ---- W1 A-frags (natural layout) ----
    bf16x8 w1f[4][2];
    #pragma unroll
    for (int mt = 0; mt < 4; ++mt)
        #pragma unroll
        for (int kb = 0; kb < 2; ++kb) {
            const float* p = W1 + (16 * mt + ml) * E_ + 32 * kb + 8 * g;
            float4 a = *(const float4*)p, bb = *(const float4*)(p + 4);
            union { bf16x8 s; unsigned u[4]; } cv;
            cv.u[0] = pk(a.x, a.y); cv.u[1] = pk(a.z, a.w);
            cv.u[2] = pk(bb.x, bb.y); cv.u[3] = pk(bb.z, bb.w);
            w1f[mt][kb] = cv.s;
        }
    // ---- W2^T B-frags, d-PERMUTED to match hs slot layout ----
    bf16x8 w2f[2][2];
    #pragma unroll
    for (int nt = 0; nt < 2; ++nt)
        #pragma unroll
        for (int kb = 0; kb < 2; ++kb) {
            const int dbase = 32 * (g & 1) + 4 * (2 * kb + (g >> 1));
            const float* p = W2 + (16 * nt + ml) * DA_ + dbase;
            float4 a  = *(const float4*)p;          // j=0..3
            float4 bb = *(const float4*)(p + 16);   // j=4..7 (d+16)
            union { bf16x8 s; unsigned u[4]; } cv;
            cv.u[0] = pk(a.x, a.y); cv.u[1] = pk(a.z, a.w);
            cv.u[2] = pk(bb.x, bb.y); cv.u[3] = pk(bb.z, bb.w);
            w2f[nt][kb] = cv.s;
        }

    f32x4 c3[2] = {f32x4{0,0,0,0}, f32x4{0,0,0,0}};
    float sswav0 = 0.0f, sswav1 = 0.0f;

    const int trow  = 16 * w + ml;          // this thread's token within sub-chunk
    const size_t cbase = ((size_t)b * L_ + c * (NS_ * TL_)) * E_;
    const int    mbase = b * L_ + c * (NS_ * TL_);

    // Per-lane LDS byte address for the tr_b16 reads (buffer 0):
    // e-tile w, token subtile 2g (offset imm walks kb/subtile). Each lane
    // points at its own 8B GRANULE (ml*8) of the 128B subtile; the HW
    // transpose delivers column ml to this lane.
    const unsigned xt_lane =
        (unsigned)(size_t)xtw0 + ((unsigned)w << 11) + ((unsigned)g << 8) + ((unsigned)ml << 3);

    // ---- prologue: loads for sub-chunk 0 ----
    float4 gx[2][2], mk;
    {
        const float* xr = x + cbase + (size_t)trow * E_ + 8 * g;
        gx[0][0] = *(const float4*)xr;
        gx[0][1] = *(const float4*)(xr + 4);
        gx[1][0] = *(const float4*)(xr + 32);
        gx[1][1] = *(const float4*)(xr + 36);
        mk = *(const float4*)(mask + mbase + 16 * w + 4 * g);
    }

    for (int s = 0; s < NS_; ++s) {
        unsigned* xtw = xtw0 + (s & 1) * XT_W;
        unsigned* asw = asw0 + (s & 1) * AS_W;

        // ---- pack bf16 B-frags for GEMM1 (same values feed xT) ----
        bf16x8 xf[2];
        union { bf16x8 s; unsigned u[4]; } xc[2];
        #pragma unroll
        for (int kb = 0; kb < 2; ++kb) {
            xc[kb].u[0] = pk(gx[kb][0].x, gx[kb][0].y);
            xc[kb].u[1] = pk(gx[kb][0].z, gx[kb][0].w);
            xc[kb].u[2] = pk(gx[kb][1].x, gx[kb][1].y);
            xc[kb].u[3] = pk(gx[kb][1].z, gx[kb][1].w);
            xf[kb] = xc[kb].s;
        }

        // ---- issue NEXT sub-chunk's global loads (hide under GEMM1/2) ----
        float4 gxn[2][2], mkn;
        if (s + 1 < NS_) {
            const float* xr = x + cbase + (size_t)((s + 1) * TL_ + trow) * E_ + 8 * g;
            gxn[0][0] = *(const float4*)xr;
            gxn[0][1] = *(const float4*)(xr + 4);
            gxn[1][0] = *(const float4*)(xr + 32);
            gxn[1][1] = *(const float4*)(xr + 36);
            mkn = *(const float4*)(mask + mbase + (s + 1) * TL_ + 16 * w + 4 * g);
        }

        // ---- xT subtiled store: [et][st][t&3][e&15], one b128 per kb ----
        // word = et*512 + (t>>2)*32 + (t&3)*8 + (g&1)*4 ; lane's 8 bf16 are
        // e = 32kb+8g.. -> contiguous cols 8(g&1)..+7 of subtile row t&3.
        {
            const int stoff = (trow >> 2) * 32 + (trow & 3) * 8 + (g & 1) * 4;
            #pragma unroll
            for (int kb = 0; kb < 2; ++kb) {
                const int et = 2 * kb + (g >> 1);
                *(uint4*)&xtw[et * 512 + stoff] = *(uint4*)&xc[kb].u[0];
            }
        }

        // ---- GEMM1: H^T tile (this wave's 16 tokens) ----
        f32x4 c1[4] = {f32x4{0,0,0,0}, f32x4{0,0,0,0}, f32x4{0,0,0,0}, f32x4{0,0,0,0}};
        #pragma unroll
        for (int kb = 0; kb < 2; ++kb)
            #pragma unroll
            for (int mt = 0; mt < 4; ++mt)
                c1[mt] = __builtin_amdgcn_mfma_f32_16x16x32_bf16(
                    w1f[mt][kb], xf[kb], c1[mt], 0, 0, 0);

        // ---- tanh -> hs: lane's 16 values CONTIGUOUS (2 b128 writes) ----
        {
            float th[4][4];
            #pragma unroll
            for (int mt = 0; mt < 4; ++mt)
                #pragma unroll
                for (int reg = 0; reg < 4; ++reg)
                    th[mt][reg] = fast_tanh(c1[mt][reg]);
            uint4 ua, ub;
            ua.x = pk(th[0][0], th[0][1]); ua.y = pk(th[0][2], th[0][3]);
            ua.z = pk(th[1][0], th[1][1]); ua.w = pk(th[1][2], th[1][3]);
            ub.x = pk(th[2][0], th[2][1]); ub.y = pk(th[2][2], th[2][3]);
            ub.z = pk(th[3][0], th[3][1]); ub.w = pk(th[3][2], th[3][3]);
            *(uint4*)&hsw[trow * HS_P + 8 * g]     = ua;
            *(uint4*)&hsw[trow * HS_P + 8 * g + 4] = ub;
        }

        // ---- GEMM2': Q[t][r] = H @ W2^T (permutation-matched frags) ----
        f32x4 c2[2] = {f32x4{0,0,0,0}, f32x4{0,0,0,0}};
        #pragma unroll
        for (int kb = 0; kb < 2; ++kb) {
            bf16x8 af = *(bf16x8*)&hsw[trow * HS_P + 16 * kb + 4 * g];
            #pragma unroll
            for (int nt = 0; nt < 2; ++nt)
                c2[nt] = __builtin_amdgcn_mfma_f32_16x16x32_bf16(
                    af, w2f[nt][kb], c2[nt], 0, 0, 0);
        }

        // ---- exp*m -> asT (b64) + lane-local ssum partials ----
        {
            const int tw = 8 * w + 2 * g;          // tokens 16w+4g.. -> word pair
            float a0 = fast_exp(c2[0][0]) * mk.x;
            float a1 = fast_exp(c2[0][1]) * mk.y;
            float a2 = fast_exp(c2[0][2]) * mk.z;
            float a3 = fast_exp(c2[0][3]) * mk.w;
            uint2 u; u.x = pk(a0, a1); u.y = pk(a2, a3);
            *(uint2*)&asw[ml * AS_P + tw] = u;
            sswav0 += bflo(u.x) + bfhi(u.x) + bflo(u.y) + bfhi(u.y);
            a0 = fast_exp(c2[1][0]) * mk.x;
            a1 = fast_exp(c2[1][1]) * mk.y;
            a2 = fast_exp(c2[1][2]) * mk.z;
            a3 = fast_exp(c2[1][3]) * mk.w;
            u.x = pk(a0, a1); u.y = pk(a2, a3);
            *(uint2*)&asw[(16 + ml) * AS_P + tw] = u;
            sswav1 += bflo(u.x) + bfhi(u.x) + bflo(u.y) + bfhi(u.y);
        }

        __syncthreads();   // asT + xT (this buffer) visible to all waves

        // ---- GEMM3: acc[r][e] += a^T @ x ; B-frag via HW transpose read ----
        {
            const unsigned xaddr = xt_lane + (unsigned)((s & 1) * (XT_W * 4));
            u32x2 t00, t01, t10, t11;
            asm volatile(
                "ds_read_b64_tr_b16 %0, %4 offset:0\n\t"     // kb0 tokens 8g+0..3
                "ds_read_b64_tr_b16 %1, %4 offset:128\n\t"   // kb0 tokens 8g+4..7
                "ds_read_b64_tr_b16 %2, %4 offset:1024\n\t"  // kb1 tokens 8g+0..3
                "ds_read_b64_tr_b16 %3, %4 offset:1152\n\t"  // kb1 tokens 8g+4..7
                "s_waitcnt lgkmcnt(0)"
                : "=&v"(t00), "=&v"(t01), "=&v"(t10), "=&v"(t11)
                : "v"(xaddr));
            __builtin_amdgcn_sched_barrier(0);
            union { bf16x8 v; u32x2 h[2]; } bx[2];
            bx[0].h[0] = t00; bx[0].h[1] = t01;
            bx[1].h[0] = t10; bx[1].h[1] = t11;
            #pragma unroll
            for (int kb = 0; kb < 2; ++kb) {
                bf16x8 bf = bx[kb].v;
                #pragma unroll
                for (int mt = 0; mt < 2; ++mt) {
                    bf16x8 af = *(bf16x8*)&asw[(16 * mt + ml) * AS_P + 16 * kb + 4 * g];
                    c3[mt] = __builtin_amdgcn_mfma_f32_16x16x32_bf16(af, bf, c3[mt], 0, 0, 0);
                }
            }
        }

        gx[0][0] = gxn[0][0]; gx[0][1] = gxn[0][1];
        gx[1][0] = gxn[1][0]; gx[1][1] = gxn[1][1];
        mk = mkn;
    }

    // ---- epilogue: partials + fused last-block finalize ----
    sswav0 += __shfl_xor(sswav0, 16); sswav0 += __shfl_xor(sswav0, 32);
    sswav1 += __shfl_xor(sswav1, 16); sswav1 += __shfl_xor(sswav1, 32);

    const size_t obase = (size_t)(b * CH_ + c) * (R_ * E_);
    const int e = 16 * w + ml;
    #pragma unroll
    for (int mt = 0; mt < 2; ++mt)
        #pragma unroll
        for (int reg = 0; reg < 4; ++reg) {
            const int r = 16 * mt + 4 * g + reg;
            accp[obase + r * E_ + e] = c3[mt][reg];
        }
    if (g == 0) {
        ssl[w * 32 + ml]      = sswav0;
        ssl[w * 32 + 16 + ml] = sswav1;
    }
    // Barrier #1: accp stores complete in L2 (syncthreads drains vmcnt),
    // ssl visible in LDS.
    __syncthreads();
    if (tid < 32)
        atomicAdd(&ssumg[b * R_ + tid],
                  ssl[tid] + ssl[32 + tid] + ssl[64 + tid] + ssl[96 + tid]);
    // Barrier #2: the 32 ssum atomics retired (vmcnt drained block-wide).
    __syncthreads();
    // Release: make this CU's L2 contents device-visible, then count.
    __threadfence();
    if (tid == 0)
        smem[0] = (atomicAdd(&cnt[b], 1u) == CH_ - 1) ? 1u : 0u;
    __syncthreads();
    if (smem[0]) {
        // Acquire: see all CH_ blocks' accp + ssumg.
        __threadfence();
        const size_t ob = (size_t)b * (R_ * E_);
        #pragma unroll
        for (int k = 0; k < 8; ++k) {
            const int o = (k << 8) + tid;          // coalesced dwords
            float num = 0.f;
            #pragma unroll
            for (int cc = 0; cc < CH_; ++cc)
                num += accp[((size_t)(b * CH_ + cc)) * (R_ * E_) + o];
            out[ob + o] = num / ssumg[b * R_ + (o >> 6)];
        }
    }
}

extern "C" void kernel_launch(void* const* d_in, const int* in_sizes, int n_in,
                              void* d_out, int out_size, void* d_ws, size_t ws_size,
                              hipStream_t stream) {
    const float* x    = (const float*)d_in[0];   // (B,L,E)
    const float* mask = (const float*)d_in[1];   // (B,L)
    const float* W1   = (const float*)d_in[2];   // (DA,E)
    const float* W2   = (const float*)d_in[3];   // (R,DA)
    float* out        = (float*)d_out;           // (B,R,E)

    float*    accp  = (float*)d_ws;                         // B*CH*R*E fp32 = 8.4 MB
    float*    ssumg = accp + (size_t)B_ * CH_ * R_ * E_;    // B*R fp32
    unsigned* cnt   = (unsigned*)(ssumg + B_ * R_);         // B u32

    // Zero the accumulation targets inside the graph (workspace is poisoned
    // by the harness each iteration). 33 KB -> ~1us.
    hipMemsetAsync(ssumg, 0, (B_ * R_ + B_) * sizeof(float), stream);

    selfbi_main<<<dim3(B_, CH_), dim3(256), 0, stream>>>(
        x, mask, W1, W2, accp, ssumg, cnt, out);
}

// Round 6
// 210.631 us; speedup vs baseline: 1.8125x; 1.8125x over previous
//
#include <hip/hip_runtime.h>
#include <hip/hip_bf16.h>

// SelfBiLayer B=256,L=2048,E=64,DA=64,R=32 -- MFMA round 13.
// Round 12's fused finalize regressed 207->382us: __threadfence() on gfx950
// lowers to buffer_wbl2 + buffer_inv (full L2 writeback/invalidate -- the
// only way to make PLAIN stores visible across non-coherent XCD L2s). 2048
// staggered L2-wide maintenance ops serialized the memory system (main
// 250us @ 335GB/s, MfmaUtil 1.3%). Round 13 keeps the fusion but uses the
// MI300-series coherent-access pattern instead of fences:
//  * accp / ssump written with __hip_atomic_store(RELAXED, AGENT scope)
//    -> sc0/sc1 write-through stores, no fence instructions emitted;
//  * __syncthreads() drains vmcnt(0) -> stores at coherence point;
//  * device-scope atomicAdd(cnt[b]) orders; last block (old==CH-1)
//    finalizes out[b] with __hip_atomic_load(RELAXED, AGENT) L2-bypass
//    reads. ZERO buffer_wbl2/buffer_inv in the binary.
//  * ssump partials are block-private (no atomics, no zeroing); only cnt
//    (1KB) is zeroed by an in-graph hipMemsetAsync.
// Main loop identical to round 10 (known-good 206.6us structure).
// Layout recap: x TOKEN-MAJOR in [e_tile(4)][tok_subtile(16)][4][16] bf16
// subtiles; GEMM3 B-frag via 4x ds_read_b64_tr_b16 (cooperative 16-lane
// granule read: lane addr = subtile_base + 8*ml -> lane gets column ml).
// Timed region note: ~156us of measured total is two 512MiB harness poison
// fills; controllable budget ~51us, HBM floor ~25us.
// Per block: (b, 512-token chunk), 8 sub-chunks of 64 tokens, 4 waves.

#define B_  256
#define L_  2048
#define E_  64
#define DA_ 64
#define R_  32
#define CH_ 4
#define NS_ 8
#define TL_ 64

typedef __attribute__((ext_vector_type(8))) short bf16x8;
typedef __attribute__((ext_vector_type(4))) float f32x4;
typedef __attribute__((ext_vector_type(2))) unsigned int u32x2;

// LDS (dword units).
#define HS_P 36
#define AS_P 36
#define HS_W (64 * HS_P)     // 2304
#define XT_W 2048            // per buffer: 4 e-tiles * 16 subtiles * 128B
#define AS_W (32 * AS_P)     // 1152 per buffer
// hs + 2*xt + 2*as + 128 ssl = 8832 words = 35328 B -> 4 blocks/CU

__device__ __forceinline__ unsigned pk(float a, float b) {
    __hip_bfloat162 h = __float22bfloat162_rn(float2{a, b});
    union { __hip_bfloat162 h2; unsigned u; } cv; cv.h2 = h;
    return cv.u;
}
__device__ __forceinline__ float bflo(unsigned u) { return __uint_as_float(u << 16); }
__device__ __forceinline__ float bfhi(unsigned u) { return __uint_as_float(u & 0xFFFF0000u); }
__device__ __forceinline__ float fast_tanh(float v) {
    float e = __builtin_amdgcn_exp2f(v * 2.885390082f);
    float r = __builtin_amdgcn_rcpf(e + 1.0f);
    return fmaf(-2.0f, r, 1.0f);
}
__device__ __forceinline__ float fast_exp(float v) {
    return __builtin_amdgcn_exp2f(v * 1.442695041f);
}

__device__ __forceinline__ void st_agent(float* p, float v) {
    __hip_atomic_store(p, v, __ATOMIC_RELAXED, __HIP_MEMORY_SCOPE_AGENT);
}
__device__ __forceinline__ float ld_agent(const float* p) {
    return __hip_atomic_load(p, __ATOMIC_RELAXED, __HIP_MEMORY_SCOPE_AGENT);
}

__launch_bounds__(256, 4)
__global__ void selfbi_main(const float* __restrict__ x,
                            const float* __restrict__ mask,
                            const float* __restrict__ W1,
                            const float* __restrict__ W2,
                            float* __restrict__ accp,
                            float* __restrict__ ssump,
                            unsigned* __restrict__ cnt,
                            float* __restrict__ out) {
    __shared__ __align__(16) unsigned smem[HS_W + 2 * XT_W + 2 * AS_W + 128];
    unsigned* hsw  = smem;                       // H token-major, d-PERMUTED slots
    unsigned* xtw0 = smem + HS_W;                // x subtiled token-major, dbuf
    unsigned* asw0 = xtw0 + 2 * XT_W;            // asT[r][t], double-buffered
    float*    ssl  = (float*)(asw0 + 2 * AS_W);  // per-wave ssum partials

    const int b    = blockIdx.x;
    const int c    = blockIdx.y;
    const int tid  = threadIdx.x;
    const int w    = tid >> 6;
    const int lane = tid & 63;
    const int g    = lane >> 4;     // k-octet group
    const int ml   = lane & 15;     // m/n lane

    // ---- W1 A-frags (natural layout) ----
    bf16x8 w1f[4][2];
    #pragma unroll
    for (int mt = 0; mt < 4; ++mt)
        #pragma unroll
        for (int kb = 0; kb < 2; ++kb) {
            const float* p = W1 + (16 * mt + ml) * E_ + 32 * kb + 8 * g;
            float4 a = *(const float4*)p, bb = *(const float4*)(p + 4);
            union { bf16x8 s; unsigned u[4]; } cv;
            cv.u[0] = pk(a.x, a.y); cv.u[1] = pk(a.z, a.w);
            cv.u[2] = pk(bb.x, bb.y); cv.u[3] = pk(bb.z, bb.w);
            w1f[mt][kb] = cv.s;
        }
    // ---- W2^T B-frags, d-PERMUTED to match hs slot layout ----
    bf16x8 w2f[2][2];
    #pragma unroll
    for (int nt = 0; nt < 2; ++nt)
        #pragma unroll
        for (int kb = 0; kb < 2; ++kb) {
            const int dbase = 32 * (g & 1) + 4 * (2 * kb + (g >> 1));
            const float* p = W2 + (16 * nt + ml) * DA_ + dbase;
            float4 a  = *(const float4*)p;          // j=0..3
            float4 bb = *(const float4*)(p + 16);   // j=4..7 (d+16)
            union { bf16x8 s; unsigned u[4]; } cv;
            cv.u[0] = pk(a.x, a.y); cv.u[1] = pk(a.z, a.w);
            cv.u[2] = pk(bb.x, bb.y); cv.u[3] = pk(bb.z, bb.w);
            w2f[nt][kb] = cv.s;
        }

    f32x4 c3[2] = {f32x4{0,0,0,0}, f32x4{0,0,0,0}};
    float sswav0 = 0.0f, sswav1 = 0.0f;

    const int trow  = 16 * w + ml;          // this thread's token within sub-chunk
    const size_t cbase = ((size_t)b * L_ + c * (NS_ * TL_)) * E_;
    const int    mbase = b * L_ + c * (NS_ * TL_);

    // Per-lane LDS byte address for the tr_b16 reads (buffer 0):
    // e-tile w, token subtile 2g (offset imm walks kb/subtile). Each lane
    // points at its own 8B GRANULE (ml*8) of the 128B subtile; the HW
    // transpose delivers column ml to this lane.
    const unsigned xt_lane =
        (unsigned)(size_t)xtw0 + ((unsigned)w << 11) + ((unsigned)g << 8) + ((unsigned)ml << 3);

    // ---- prologue: loads for sub-chunk 0 ----
    float4 gx[2][2], mk;
    {
        const float* xr = x + cbase + (size_t)trow * E_ + 8 * g;
        gx[0][0] = *(const float4*)xr;
        gx[0][1] = *(const float4*)(xr + 4);
        gx[1][0] = *(const float4*)(xr + 32);
        gx[1][1] = *(const float4*)(xr + 36);
        mk = *(const float4*)(mask + mbase + 16 * w + 4 * g);
    }

    for (int s = 0; s < NS_; ++s) {
        unsigned* xtw = xtw0 + (s & 1) * XT_W;
        unsigned* asw = asw0 + (s & 1) * AS_W;

        // ---- pack bf16 B-frags for GEMM1 (same values feed xT) ----
        bf16x8 xf[2];
        union { bf16x8 s; unsigned u[4]; } xc[2];
        #pragma unroll
        for (int kb = 0; kb < 2; ++kb) {
            xc[kb].u[0] = pk(gx[kb][0].x, gx[kb][0].y);
            xc[kb].u[1] = pk(gx[kb][0].z, gx[kb][0].w);
            xc[kb].u[2] = pk(gx[kb][1].x, gx[kb][1].y);
            xc[kb].u[3] = pk(gx[kb][1].z, gx[kb][1].w);
            xf[kb] = xc[kb].s;
        }

        // ---- issue NEXT sub-chunk's global loads (hide under GEMM1/2) ----
        float4 gxn[2][2], mkn;
        if (s + 1 < NS_) {
            const float* xr = x + cbase + (size_t)((s + 1) * TL_ + trow) * E_ + 8 * g;
            gxn[0][0] = *(const float4*)xr;
            gxn[0][1] = *(const float4*)(xr + 4);
            gxn[1][0] = *(const float4*)(xr + 32);
            gxn[1][1] = *(const float4*)(xr + 36);
            mkn = *(const float4*)(mask + mbase + (s + 1) * TL_ + 16 * w + 4 * g);
        }

        // ---- xT subtiled store: [et][st][t&3][e&15], one b128 per kb ----
        // word = et*512 + (t>>2)*32 + (t&3)*8 + (g&1)*4 ; lane's 8 bf16 are
        // e = 32kb+8g.. -> contiguous cols 8(g&1)..+7 of subtile row t&3.
        {
            const int stoff = (trow >> 2) * 32 + (trow & 3) * 8 + (g & 1) * 4;
            #pragma unroll
            for (int kb = 0; kb < 2; ++kb) {
                const int et = 2 * kb + (g >> 1);
                *(uint4*)&xtw[et * 512 + stoff] = *(uint4*)&xc[kb].u[0];
            }
        }

        // ---- GEMM1: H^T tile (this wave's 16 tokens) ----
        f32x4 c1[4] = {f32x4{0,0,0,0}, f32x4{0,0,0,0}, f32x4{0,0,0,0}, f32x4{0,0,0,0}};
        #pragma unroll
        for (int kb = 0; kb < 2; ++kb)
            #pragma unroll
            for (int mt = 0; mt < 4; ++mt)
                c1[mt] = __builtin_amdgcn_mfma_f32_16x16x32_bf16(
                    w1f[mt][kb], xf[kb], c1[mt], 0, 0, 0);

        // ---- tanh -> hs: lane's 16 values CONTIGUOUS (2 b128 writes) ----
        {
            float th[4][4];
            #pragma unroll
            for (int mt = 0; mt < 4; ++mt)
                #pragma unroll
                for (int reg = 0; reg < 4; ++reg)
                    th[mt][reg] = fast_tanh(c1[mt][reg]);
            uint4 ua, ub;
            ua.x = pk(th[0][0], th[0][1]); ua.y = pk(th[0][2], th[0][3]);
            ua.z = pk(th[1][0], th[1][1]); ua.w = pk(th[1][2], th[1][3]);
            ub.x = pk(th[2][0], th[2][1]); ub.y = pk(th[2][2], th[2][3]);
            ub.z = pk(th[3][0], th[3][1]); ub.w = pk(th[3][2], th[3][3]);
            *(uint4*)&hsw[trow * HS_P + 8 * g]     = ua;
            *(uint4*)&hsw[trow * HS_P + 8 * g + 4] = ub;
        }

        // ---- GEMM2': Q[t][r] = H @ W2^T (permutation-matched frags) ----
        f32x4 c2[2] = {f32x4{0,0,0,0}, f32x4{0,0,0,0}};
        #pragma unroll
        for (int kb = 0; kb < 2; ++kb) {
            bf16x8 af = *(bf16x8*)&hsw[trow * HS_P + 16 * kb + 4 * g];
            #pragma unroll
            for (int nt = 0; nt < 2; ++nt)
                c2[nt] = __builtin_amdgcn_mfma_f32_16x16x32_bf16(
                    af, w2f[nt][kb], c2[nt], 0, 0, 0);
        }

        // ---- exp*m -> asT (b64) + lane-local ssum partials ----
        {
            const int tw = 8 * w + 2 * g;          // tokens 16w+4g.. -> word pair
            float a0 = fast_exp(c2[0][0]) * mk.x;
            float a1 = fast_exp(c2[0][1]) * mk.y;
            float a2 = fast_exp(c2[0][2]) * mk.z;
            float a3 = fast_exp(c2[0][3]) * mk.w;
            uint2 u; u.x = pk(a0, a1); u.y = pk(a2, a3);
            *(uint2*)&asw[ml * AS_P + tw] = u;
            sswav0 += bflo(u.x) + bfhi(u.x) + bflo(u.y) + bfhi(u.y);
            a0 = fast_exp(c2[1][0]) * mk.x;
            a1 = fast_exp(c2[1][1]) * mk.y;
            a2 = fast_exp(c2[1][2]) * mk.z;
            a3 = fast_exp(c2[1][3]) * mk.w;
            u.x = pk(a0, a1); u.y = pk(a2, a3);
            *(uint2*)&asw[(16 + ml) * AS_P + tw] = u;
            sswav1 += bflo(u.x) + bfhi(u.x) + bflo(u.y) + bfhi(u.y);
        }

        __syncthreads();   // asT + xT (this buffer) visible to all waves

        // ---- GEMM3: acc[r][e] += a^T @ x ; B-frag via HW transpose read ----
        {
            const unsigned xaddr = xt_lane + (unsigned)((s & 1) * (XT_W * 4));
            u32x2 t00, t01, t10, t11;
            asm volatile(
                "ds_read_b64_tr_b16 %0, %4 offset:0\n\t"     // kb0 tokens 8g+0..3
                "ds_read_b64_tr_b16 %1, %4 offset:128\n\t"   // kb0 tokens 8g+4..7
                "ds_read_b64_tr_b16 %2, %4 offset:1024\n\t"  // kb1 tokens 8g+0..3
                "ds_read_b64_tr_b16 %3, %4 offset:1152\n\t"  // kb1 tokens 8g+4..7
                "s_waitcnt lgkmcnt(0)"
                : "=&v"(t00), "=&v"(t01), "=&v"(t10), "=&v"(t11)
                : "v"(xaddr));
            __builtin_amdgcn_sched_barrier(0);
            union { bf16x8 v; u32x2 h[2]; } bx[2];
            bx[0].h[0] = t00; bx[0].h[1] = t01;
            bx[1].h[0] = t10; bx[1].h[1] = t11;
            #pragma unroll
            for (int kb = 0; kb < 2; ++kb) {
                bf16x8 bf = bx[kb].v;
                #pragma unroll
                for (int mt = 0; mt < 2; ++mt) {
                    bf16x8 af = *(bf16x8*)&asw[(16 * mt + ml) * AS_P + 16 * kb + 4 * g];
                    c3[mt] = __builtin_amdgcn_mfma_f32_16x16x32_bf16(af, bf, c3[mt], 0, 0, 0);
                }
            }
        }

        gx[0][0] = gxn[0][0]; gx[0][1] = gxn[0][1];
        gx[1][0] = gxn[1][0]; gx[1][1] = gxn[1][1];
        mk = mkn;
    }

    // ---- epilogue: agent-coherent partial stores + last-block finalize ----
    sswav0 += __shfl_xor(sswav0, 16); sswav0 += __shfl_xor(sswav0, 32);
    sswav1 += __shfl_xor(sswav1, 16); sswav1 += __shfl_xor(sswav1, 32);

    const size_t obase = (size_t)(b * CH_ + c) * (R_ * E_);
    const int e = 16 * w + ml;
    #pragma unroll
    for (int mt = 0; mt < 2; ++mt)
        #pragma unroll
        for (int reg = 0; reg < 4; ++reg) {
            const int r = 16 * mt + 4 * g + reg;
            st_agent(&accp[obase + r * E_ + e], c3[mt][reg]);
        }
    if (g == 0) {
        ssl[w * 32 + ml]      = sswav0;
        ssl[w * 32 + 16 + ml] = sswav1;
    }
    __syncthreads();
    if (tid < 32)
        st_agent(&ssump[(b * CH_ + c) * R_ + tid],
                 ssl[tid] + ssl[32 + tid] + ssl[64 + tid] + ssl[96 + tid]);
    // syncthreads drains vmcnt(0): all agent (write-through) stores have
    // reached the coherence point before any thread proceeds to the count.
    __syncthreads();
    if (tid == 0)
        smem[0] = (atomicAdd(&cnt[b], 1u) == CH_ - 1) ? 1u : 0u;
    __syncthreads();
    if (smem[0]) {
        // Last block for this b: all CH_ blocks' agent stores are at the
        // coherence point (their vmcnt drains preceded their cnt bumps);
        // agent loads bypass the local L2 and read it.
        const size_t ob = (size_t)b * (R_ * E_);
        #pragma unroll
        for (int k = 0; k < 8; ++k) {
            const int o = (k << 8) + tid;          // coalesced dwords
            const int r = o >> 6;
            float num = 0.f, den = 0.f;
            #pragma unroll
            for (int cc = 0; cc < CH_; ++cc) {
                num += ld_agent(&accp[((size_t)(b * CH_ + cc)) * (R_ * E_) + o]);
                den += ld_agent(&ssump[(b * CH_ + cc) * R_ + r]);
            }
            out[ob + o] = num / den;
        }
    }
}

extern "C" void kernel_launch(void* const* d_in, const int* in_sizes, int n_in,
                              void* d_out, int out_size, void* d_ws, size_t ws_size,
                              hipStream_t stream) {
    const float* x    = (const float*)d_in[0];   // (B,L,E)
    const float* mask = (const float*)d_in[1];   // (B,L)
    const float* W1   = (const float*)d_in[2];   // (DA,E)
    const float* W2   = (const float*)d_in[3];   // (R,DA)
    float* out        = (float*)d_out;           // (B,R,E)

    float*    accp  = (float*)d_ws;                         // B*CH*R*E fp32 = 8.4 MB
    float*    ssump = accp + (size_t)B_ * CH_ * R_ * E_;    // B*CH*R fp32 (private per block)
    unsigned* cnt   = (unsigned*)(ssump + B_ * CH_ * R_);   // B u32

    // Only cnt needs zeroing (ssump/accp cells are each written exactly once
    // by their owning block). 1 KB memset inside the graph.
    hipMemsetAsync(cnt, 0, B_ * sizeof(unsigned), stream);

    selfbi_main<<<dim3(B_, CH_), dim3(256), 0, stream>>>(
        x, mask, W1, W2, accp, ssump, cnt, out);
}